// Round 1
// baseline (928.448 us; speedup 1.0000x reference)
//
#include <hip/hip_runtime.h>
#include <math.h>

#define Bq 16
#define Tq 34
#define Nq 1000
#define Cq 32      // CIN == DC == 32
#define OCq 64
#define Eq 16000
#define TPq 32     // T - dilation
#define Gq (Bq*TPq)  // 512 graphs

// ---------------------------------------------------------------------------
// K1: fused dilated gated conv  -> out1 [B,32,N,32]  and  xw = gated @ Wgcn^T
// one thread per (b,n,t) position; weights staged in LDS (broadcast reads)
// ---------------------------------------------------------------------------
__global__ __launch_bounds__(256) void k_conv(
    const float* __restrict__ x,
    const float* __restrict__ wg1, const float* __restrict__ bg1,
    const float* __restrict__ wg2, const float* __restrict__ bg2,
    const float* __restrict__ wgcn,
    float* __restrict__ out1, float* __restrict__ xw)
{
    __shared__ float w1a[Cq*Cq], w1b[Cq*Cq], w2a[Cq*Cq], w2b[Cq*Cq];
    __shared__ float wgcT[Cq*Cq];   // wgcT[d][c] = wgcn[c][d]
    __shared__ float b1s[Cq], b2s[Cq];
    const int tid = threadIdx.x;
    for (int i = tid; i < Cq*Cq; i += 256) {
        w1a[i] = wg1[2*i];  w1b[i] = wg1[2*i+1];
        w2a[i] = wg2[2*i];  w2b[i] = wg2[2*i+1];
        wgcT[i] = wgcn[(i & 31)*Cq + (i >> 5)];
    }
    if (tid < Cq) { b1s[tid] = bg1[tid]; b2s[tid] = bg2[tid]; }
    __syncthreads();

    // p = (b*N + n)*32 + t  -> lanes consecutive in t (coalesced out1 stores)
    const int p  = blockIdx.x*256 + tid;
    const int t  = p & 31;
    const int bn = p >> 5;
    const int n  = bn % Nq;
    const int b  = bn / Nq;

    const float* x0p = x + (size_t)((b*Tq + t)*Nq + n)*Cq;
    const float* x1p = x0p + 2*Nq*Cq;      // tap at t+dilation
    float x0[Cq], x1[Cq];
    #pragma unroll
    for (int c4 = 0; c4 < Cq/4; c4++) {
        float4 a = ((const float4*)x0p)[c4];
        x0[4*c4+0]=a.x; x0[4*c4+1]=a.y; x0[4*c4+2]=a.z; x0[4*c4+3]=a.w;
        float4 bb = ((const float4*)x1p)[c4];
        x1[4*c4+0]=bb.x; x1[4*c4+1]=bb.y; x1[4*c4+2]=bb.z; x1[4*c4+3]=bb.w;
    }

    float xwa[Cq];
    #pragma unroll
    for (int c = 0; c < Cq; c++) xwa[c] = 0.f;

    float* o1base = out1 + (size_t)b*(Cq*Nq*TPq) + n*TPq + t;

    #pragma unroll 4
    for (int o = 0; o < Cq; o++) {
        float a1 = b1s[o], a2 = b2s[o];
        #pragma unroll
        for (int c4 = 0; c4 < 8; c4++) {
            const float4 va = *(const float4*)&w1a[o*Cq + 4*c4];
            const float4 vb = *(const float4*)&w1b[o*Cq + 4*c4];
            const float4 vc = *(const float4*)&w2a[o*Cq + 4*c4];
            const float4 vd = *(const float4*)&w2b[o*Cq + 4*c4];
            a1 += x0[4*c4+0]*va.x + x0[4*c4+1]*va.y + x0[4*c4+2]*va.z + x0[4*c4+3]*va.w;
            a1 += x1[4*c4+0]*vb.x + x1[4*c4+1]*vb.y + x1[4*c4+2]*vb.z + x1[4*c4+3]*vb.w;
            a2 += x0[4*c4+0]*vc.x + x0[4*c4+1]*vc.y + x0[4*c4+2]*vc.z + x0[4*c4+3]*vc.w;
            a2 += x1[4*c4+0]*vd.x + x1[4*c4+1]*vd.y + x1[4*c4+2]*vd.z + x1[4*c4+3]*vd.w;
        }
        const float go = tanhf(a1) * (1.f / (1.f + expf(-a2)));
        o1base[(size_t)o * (Nq*TPq)] = go;
        #pragma unroll
        for (int c4 = 0; c4 < 8; c4++) {
            const float4 w = *(const float4*)&wgcT[o*Cq + 4*c4];
            xwa[4*c4+0] += go*w.x; xwa[4*c4+1] += go*w.y;
            xwa[4*c4+2] += go*w.z; xwa[4*c4+3] += go*w.w;
        }
    }

    // xw row q = (b*32 + t)*N + n  (graph index layout for the GCN)
    float4* xwrow = (float4*)(xw + (size_t)((b*TPq + t)*Nq + n)*Cq);
    #pragma unroll
    for (int c4 = 0; c4 < 8; c4++) {
        float4 v; v.x = xwa[4*c4+0]; v.y = xwa[4*c4+1];
        v.z = xwa[4*c4+2]; v.w = xwa[4*c4+3];
        xwrow[c4] = v;
    }
}

// ---------------------------------------------------------------------------
// Graph prep: degree/count -> scan -> CSR fill (rows = dst, symmetric norm)
// ---------------------------------------------------------------------------
__global__ void k_graph_init(float* deg, int* cnt)
{
    int n = blockIdx.x*256 + threadIdx.x;
    if (n < Nq) { deg[n] = 1.0f; cnt[n] = 0; }   // self-loop weight 1
}

__global__ void k_graph_count(const int* __restrict__ ei,
                              const float* __restrict__ ew,
                              float* deg, int* cnt)
{
    int e = blockIdx.x*256 + threadIdx.x;
    if (e < Eq) {
        int d = ei[Eq + e];
        atomicAdd(&deg[d], ew[e]);
        atomicAdd(&cnt[d], 1);
    }
}

__global__ __launch_bounds__(1024) void k_graph_scan(
    const float* __restrict__ deg, const int* __restrict__ cnt,
    float* dis, int* rowstart, int* pos)
{
    __shared__ int s[1024];
    const int tid = threadIdx.x;
    const int v = (tid < Nq) ? cnt[tid] : 0;
    s[tid] = v;
    __syncthreads();
    for (int off = 1; off < 1024; off <<= 1) {
        int add = (tid >= off) ? s[tid - off] : 0;
        __syncthreads();
        s[tid] += add;
        __syncthreads();
    }
    if (tid < Nq) {
        int excl = s[tid] - v;
        rowstart[tid] = excl;
        pos[tid] = excl;
        dis[tid] = rsqrtf(deg[tid]);   // deg >= 1 always (self loop)
        if (tid == Nq-1) rowstart[Nq] = s[tid];
    }
}

__global__ void k_graph_fill(const int* __restrict__ ei,
                             const float* __restrict__ ew,
                             const float* __restrict__ dis,
                             int* pos, int* col, float* val)
{
    int e = blockIdx.x*256 + threadIdx.x;
    if (e < Eq) {
        int srce = ei[e], d = ei[Eq + e];
        int slot = atomicAdd(&pos[d], 1);
        col[slot] = srce;
        val[slot] = dis[srce] * ew[e] * dis[d];
    }
}

// ---------------------------------------------------------------------------
// K3: sparse propagate (A @ xw + b_gcn) fused with 1x1 out-conv -> y
// block = 8 positions x 32 lanes(c); LDS tile bridges c-layout -> o-layout
// ---------------------------------------------------------------------------
__global__ __launch_bounds__(256) void k_gcn(
    const float* __restrict__ xw, const int* __restrict__ rowstart,
    const int* __restrict__ col, const float* __restrict__ val,
    const float* __restrict__ dis, const float* __restrict__ bgcn,
    const float* __restrict__ wout, const float* __restrict__ bout,
    float* __restrict__ y)
{
    __shared__ float woT[Cq*65];      // woT[c*65 + o] = wout[o*32 + c] (padded)
    __shared__ float gt[8][Cq];
    __shared__ float bg[Cq], bo[OCq];
    const int tid = threadIdx.x;
    for (int i = tid; i < OCq*Cq; i += 256) {
        int o = i >> 5, c = i & 31;
        woT[c*65 + o] = wout[i];
    }
    if (tid < Cq) bg[tid] = bgcn[tid];
    if (tid >= 64 && tid < 64 + OCq) bo[tid - 64] = bout[tid - 64];
    __syncthreads();

    const int lane = tid & 31, pp = tid >> 5;
    const int q = blockIdx.x*8 + pp;          // q = g*N + i
    const int g = q / Nq;
    const int i = q - g*Nq;

    const float dii = dis[i];
    const float* __restrict__ xwg = xw + (size_t)g*(Nq*Cq);
    float acc = dii*dii * xwg[i*Cq + lane];   // self loop
    const int r0 = rowstart[i], r1 = rowstart[i+1];
    for (int k = r0; k < r1; k++) {
        acc += val[k] * xwg[col[k]*Cq + lane];
    }
    gt[pp][lane] = acc + bg[lane];
    __syncthreads();

    float y0 = bo[lane], y1 = bo[32 + lane];
    #pragma unroll
    for (int c = 0; c < Cq; c++) {
        const float gc = gt[pp][c];
        y0 += gc * woT[c*65 + lane];
        y1 += gc * woT[c*65 + 32 + lane];
    }
    y[(size_t)q*OCq + lane]      = y0;
    y[(size_t)q*OCq + 32 + lane] = y1;
}

// ---------------------------------------------------------------------------
extern "C" void kernel_launch(void* const* d_in, const int* in_sizes, int n_in,
                              void* d_out, int out_size, void* d_ws, size_t ws_size,
                              hipStream_t stream)
{
    const float* x    = (const float*)d_in[0];
    const int*   ei   = (const int*)  d_in[1];
    const float* ew   = (const float*)d_in[2];
    const float* wg1  = (const float*)d_in[3];
    const float* bg1  = (const float*)d_in[4];
    const float* wg2  = (const float*)d_in[5];
    const float* bg2  = (const float*)d_in[6];
    const float* wgcn = (const float*)d_in[7];
    const float* bgcn = (const float*)d_in[8];
    const float* wout = (const float*)d_in[9];
    const float* bout = (const float*)d_in[10];

    float* out1 = (float*)d_out;                         // [B,32,N,32]
    float* y    = out1 + (size_t)Bq*Cq*Nq*TPq;           // [B,32,N,64]

    char* ws = (char*)d_ws;
    float* xw  = (float*)ws; ws += sizeof(float)*(size_t)Gq*Nq*Cq;  // 65.5 MB
    float* deg = (float*)ws; ws += sizeof(float)*Nq;
    float* dis = (float*)ws; ws += sizeof(float)*Nq;
    float* val = (float*)ws; ws += sizeof(float)*Eq;
    int*   col = (int*)ws;   ws += sizeof(int)*Eq;
    int*   cnt = (int*)ws;   ws += sizeof(int)*Nq;
    int*   rowstart = (int*)ws; ws += sizeof(int)*(Nq+1);
    int*   pos = (int*)ws;   ws += sizeof(int)*Nq;

    k_conv<<<(Bq*Nq*TPq)/256, 256, 0, stream>>>(x, wg1, bg1, wg2, bg2, wgcn,
                                                out1, xw);
    k_graph_init <<<(Nq+255)/256, 256, 0, stream>>>(deg, cnt);
    k_graph_count<<<(Eq+255)/256, 256, 0, stream>>>(ei, ew, deg, cnt);
    k_graph_scan <<<1, 1024, 0, stream>>>(deg, cnt, dis, rowstart, pos);
    k_graph_fill <<<(Eq+255)/256, 256, 0, stream>>>(ei, ew, dis, pos, col, val);
    k_gcn<<<(Gq*Nq)/8, 256, 0, stream>>>(xw, rowstart, col, val, dis,
                                         bgcn, wout, bout, y);
}

// Round 2
// 601.270 us; speedup vs baseline: 1.5441x; 1.5441x over previous
//
#include <hip/hip_runtime.h>
#include <math.h>

#define Bq 16
#define Tq 34
#define Nq 1000
#define Cq 32      // CIN == DC == 32
#define OCq 64
#define Eq 16000
#define TPq 32     // T - dilation
#define Gq (Bq*TPq)  // 512 graphs
#define NG8 (Nq/8)   // 125

__device__ __forceinline__ float fast_tanh(float x) {
    float xc = fminf(fmaxf(x, -15.f), 15.f);
    float u  = __expf(2.f * xc);
    return 1.f - 2.f * __builtin_amdgcn_rcpf(u + 1.f);
}
__device__ __forceinline__ float fast_sigmoid(float x) {
    float xc = fminf(fmaxf(x, -30.f), 30.f);
    return __builtin_amdgcn_rcpf(1.f + __expf(-xc));
}

// ---------------------------------------------------------------------------
// K1: fused dilated gated conv -> out1 [B,32,N,32], and xw_t[n][g][c] (swizzled)
// block = 8 n x 32 t; x tile staged in LDS (coalesced); gate weights read
// with uniform indices (scalar loads).
// ---------------------------------------------------------------------------
__global__ __launch_bounds__(256) void k_conv(
    const float* __restrict__ x,
    const float* __restrict__ wg1, const float* __restrict__ bg1,
    const float* __restrict__ wg2, const float* __restrict__ bg2,
    const float* __restrict__ wgcn,
    float* __restrict__ out1, float* __restrict__ xwt)
{
    __shared__ float xs[34*260];      // [t][n*32+c], row stride 260 (pad 4)
    __shared__ float wgcT[Cq*Cq];     // wgcT[d*32+c] = wgcn[c*32+d]
    const int tid = threadIdx.x;
    const int b   = blockIdx.x / NG8;
    const int n0  = (blockIdx.x % NG8) * 8;

    for (int i = tid; i < Cq*Cq; i += 256)
        wgcT[i] = wgcn[(i & 31)*Cq + (i >> 5)];
    const float* xsrc = x + ((size_t)b*Tq*Nq + n0)*Cq;
    #pragma unroll
    for (int j = 0; j < Tq; j++)
        xs[j*260 + tid] = xsrc[(size_t)j*Nq*Cq + tid];
    __syncthreads();

    const int t  = tid & 31;
    const int nl = tid >> 5;
    const int n  = n0 + nl;

    float x0[Cq], x1[Cq];
    #pragma unroll
    for (int c4 = 0; c4 < 8; c4++) {
        float4 a = *(const float4*)&xs[t*260 + nl*32 + 4*c4];
        x0[4*c4+0]=a.x; x0[4*c4+1]=a.y; x0[4*c4+2]=a.z; x0[4*c4+3]=a.w;
        float4 bb = *(const float4*)&xs[(t+2)*260 + nl*32 + 4*c4];
        x1[4*c4+0]=bb.x; x1[4*c4+1]=bb.y; x1[4*c4+2]=bb.z; x1[4*c4+3]=bb.w;
    }

    float xwa[Cq];
    #pragma unroll
    for (int c = 0; c < Cq; c++) xwa[c] = 0.f;

    float* o1base = out1 + (size_t)b*(Cq*Nq*TPq) + n*TPq + t;

    #pragma unroll
    for (int o = 0; o < Cq; o++) {
        float a1 = bg1[o], a2 = bg2[o];     // uniform -> scalar loads
        const float* w1 = wg1 + o*2*Cq;     // [c][tap] interleaved
        const float* w2 = wg2 + o*2*Cq;
        #pragma unroll
        for (int c = 0; c < Cq; c++) {
            a1 = fmaf(x0[c], w1[2*c],   a1);
            a1 = fmaf(x1[c], w1[2*c+1], a1);
            a2 = fmaf(x0[c], w2[2*c],   a2);
            a2 = fmaf(x1[c], w2[2*c+1], a2);
        }
        const float go = fast_tanh(a1) * fast_sigmoid(a2);
        o1base[(size_t)o * (Nq*TPq)] = go;
        #pragma unroll
        for (int c4 = 0; c4 < 8; c4++) {
            const float4 w = *(const float4*)&wgcT[o*Cq + 4*c4];
            xwa[4*c4+0] = fmaf(go, w.x, xwa[4*c4+0]);
            xwa[4*c4+1] = fmaf(go, w.y, xwa[4*c4+1]);
            xwa[4*c4+2] = fmaf(go, w.z, xwa[4*c4+2]);
            xwa[4*c4+3] = fmaf(go, w.w, xwa[4*c4+3]);
        }
    }

    // swizzled write: graph g = b*32+t owns float4 slot j*256 + (g>>1) of row n,
    // j = (g&1)*8 + c4  (matches k_gcn's per-thread coalesced read layout)
    float4* xwrow = (float4*)(xwt + (size_t)n*Gq*Cq);
    const int xwoff = b*16 + (t >> 1);
    const int jbase = (t & 1) * 8;
    #pragma unroll
    for (int c4 = 0; c4 < 8; c4++) {
        float4 v;
        v.x = xwa[4*c4+0]; v.y = xwa[4*c4+1];
        v.z = xwa[4*c4+2]; v.w = xwa[4*c4+3];
        xwrow[(jbase + c4)*256 + xwoff] = v;
    }
}

// ---------------------------------------------------------------------------
// Graph prep: degree/count -> scan -> CSR fill (rows = dst, symmetric norm)
// ---------------------------------------------------------------------------
__global__ void k_graph_init(float* deg, int* cnt)
{
    int n = blockIdx.x*256 + threadIdx.x;
    if (n < Nq) { deg[n] = 1.0f; cnt[n] = 0; }   // self-loop weight 1
}

__global__ void k_graph_count(const int* __restrict__ ei,
                              const float* __restrict__ ew,
                              float* deg, int* cnt)
{
    int e = blockIdx.x*256 + threadIdx.x;
    if (e < Eq) {
        int d = ei[Eq + e];
        atomicAdd(&deg[d], ew[e]);
        atomicAdd(&cnt[d], 1);
    }
}

__global__ __launch_bounds__(1024) void k_graph_scan(
    const float* __restrict__ deg, const int* __restrict__ cnt,
    float* dis, int* rowstart, int* pos)
{
    __shared__ int s[1024];
    const int tid = threadIdx.x;
    const int v = (tid < Nq) ? cnt[tid] : 0;
    s[tid] = v;
    __syncthreads();
    for (int off = 1; off < 1024; off <<= 1) {
        int add = (tid >= off) ? s[tid - off] : 0;
        __syncthreads();
        s[tid] += add;
        __syncthreads();
    }
    if (tid < Nq) {
        int excl = s[tid] - v;
        rowstart[tid] = excl;
        pos[tid] = excl;
        dis[tid] = rsqrtf(deg[tid]);   // deg >= 1 always (self loop)
        if (tid == Nq-1) rowstart[Nq] = s[tid];
    }
}

__global__ void k_graph_fill(const int* __restrict__ ei,
                             const float* __restrict__ ew,
                             const float* __restrict__ dis,
                             int* pos, int* col, float* val)
{
    int e = blockIdx.x*256 + threadIdx.x;
    if (e < Eq) {
        int srce = ei[e], d = ei[Eq + e];
        int slot = atomicAdd(&pos[d], 1);
        col[slot] = srce;
        val[slot] = dis[srce] * ew[e] * dis[d];
    }
}

// ---------------------------------------------------------------------------
// K3: one block per dst row i; 256 threads x (2 graphs x 32 c) accumulators.
// Per edge: one contiguous 64-KB row read, fully coalesced. Fused 1x1 conv
// epilogue entirely in registers.
// ---------------------------------------------------------------------------
__global__ __launch_bounds__(256) void k_gcn(
    const float* __restrict__ xwt, const int* __restrict__ rowstart,
    const int* __restrict__ colv, const float* __restrict__ valv,
    const float* __restrict__ dis, const float* __restrict__ bgcn,
    const float* __restrict__ wout, const float* __restrict__ bout,
    float* __restrict__ y)
{
    __shared__ float woT[Cq*OCq];   // woT[c*64+o] = wout[o*32+c]
    __shared__ int   scol[64];
    __shared__ float sval[64];
    const int tid = threadIdx.x;
    const int i   = blockIdx.x;

    for (int k = tid; k < Cq*OCq; k += 256) {
        int o = k >> 5, c = k & 31;
        woT[c*OCq + o] = wout[k];
    }

    float acc[64];                  // [0..31] = graph 2*tid, [32..63] = 2*tid+1
    #pragma unroll
    for (int j = 0; j < 64; j++) acc[j] = 0.f;

    const int r0 = rowstart[i], r1 = rowstart[i+1];
    const int total = r1 - r0 + 1;       // + self loop
    const float dii = dis[i];
    const float4* xw4 = (const float4*)xwt;

    for (int base = 0; base < total; base += 64) {
        const int cnt = min(64, total - base);
        __syncthreads();
        if (tid < cnt) {
            int k = base + tid;
            if (k == 0) { scol[tid] = i; sval[tid] = dii*dii; }
            else        { scol[tid] = colv[r0 + k - 1]; sval[tid] = valv[r0 + k - 1]; }
        }
        __syncthreads();
        for (int k = 0; k < cnt; k++) {
            const int   sc = scol[k];
            const float sv = sval[k];
            const float4* rp = xw4 + (size_t)sc*(Gq*Cq/4) + tid;
            float4 v[16];
            #pragma unroll
            for (int j = 0; j < 16; j++) v[j] = rp[j*256];
            #pragma unroll
            for (int j = 0; j < 16; j++) {
                acc[4*j+0] = fmaf(sv, v[j].x, acc[4*j+0]);
                acc[4*j+1] = fmaf(sv, v[j].y, acc[4*j+1]);
                acc[4*j+2] = fmaf(sv, v[j].z, acc[4*j+2]);
                acc[4*j+3] = fmaf(sv, v[j].w, acc[4*j+3]);
            }
        }
    }

    // + b_gcn (uniform loads)
    #pragma unroll
    for (int c4 = 0; c4 < 8; c4++) {
        const float4 bg = *(const float4*)&bgcn[4*c4];
        acc[4*c4+0]    += bg.x; acc[4*c4+1]    += bg.y;
        acc[4*c4+2]    += bg.z; acc[4*c4+3]    += bg.w;
        acc[32+4*c4+0] += bg.x; acc[32+4*c4+1] += bg.y;
        acc[32+4*c4+2] += bg.z; acc[32+4*c4+3] += bg.w;
    }

    const int gA = 2*tid, gB = 2*tid + 1;
    float* yA = y + ((size_t)gA*Nq + i)*OCq;
    float* yB = y + ((size_t)gB*Nq + i)*OCq;

    #pragma unroll
    for (int oc = 0; oc < 4; oc++) {       // 16 outputs per chunk
        float ya[16], yb[16];
        #pragma unroll
        for (int q = 0; q < 16; q++) {
            const float bv = bout[oc*16 + q];   // uniform
            ya[q] = bv; yb[q] = bv;
        }
        #pragma unroll
        for (int c = 0; c < Cq; c++) {
            const float ga = acc[c];
            const float gb = acc[32 + c];
            const float* wrow = &woT[c*OCq + oc*16];
            #pragma unroll
            for (int q4 = 0; q4 < 4; q4++) {
                const float4 w = *(const float4*)&wrow[4*q4];
                ya[4*q4+0] = fmaf(ga, w.x, ya[4*q4+0]);
                ya[4*q4+1] = fmaf(ga, w.y, ya[4*q4+1]);
                ya[4*q4+2] = fmaf(ga, w.z, ya[4*q4+2]);
                ya[4*q4+3] = fmaf(ga, w.w, ya[4*q4+3]);
                yb[4*q4+0] = fmaf(gb, w.x, yb[4*q4+0]);
                yb[4*q4+1] = fmaf(gb, w.y, yb[4*q4+1]);
                yb[4*q4+2] = fmaf(gb, w.z, yb[4*q4+2]);
                yb[4*q4+3] = fmaf(gb, w.w, yb[4*q4+3]);
            }
        }
        #pragma unroll
        for (int q4 = 0; q4 < 4; q4++) {
            float4 va, vb;
            va.x = ya[4*q4+0]; va.y = ya[4*q4+1]; va.z = ya[4*q4+2]; va.w = ya[4*q4+3];
            vb.x = yb[4*q4+0]; vb.y = yb[4*q4+1]; vb.z = yb[4*q4+2]; vb.w = yb[4*q4+3];
            *(float4*)&yA[oc*16 + 4*q4] = va;
            *(float4*)&yB[oc*16 + 4*q4] = vb;
        }
    }
}

// ---------------------------------------------------------------------------
extern "C" void kernel_launch(void* const* d_in, const int* in_sizes, int n_in,
                              void* d_out, int out_size, void* d_ws, size_t ws_size,
                              hipStream_t stream)
{
    const float* x    = (const float*)d_in[0];
    const int*   ei   = (const int*)  d_in[1];
    const float* ew   = (const float*)d_in[2];
    const float* wg1  = (const float*)d_in[3];
    const float* bg1  = (const float*)d_in[4];
    const float* wg2  = (const float*)d_in[5];
    const float* bg2  = (const float*)d_in[6];
    const float* wgcn = (const float*)d_in[7];
    const float* bgcn = (const float*)d_in[8];
    const float* wout = (const float*)d_in[9];
    const float* bout = (const float*)d_in[10];

    float* out1 = (float*)d_out;                         // [B,32,N,32]
    float* y    = out1 + (size_t)Bq*Cq*Nq*TPq;           // [B,32,N,64]

    char* ws = (char*)d_ws;
    float* xwt = (float*)ws; ws += sizeof(float)*(size_t)Nq*Gq*Cq;  // 65.5 MB
    float* deg = (float*)ws; ws += sizeof(float)*Nq;
    float* dis = (float*)ws; ws += sizeof(float)*Nq;
    float* val = (float*)ws; ws += sizeof(float)*Eq;
    int*   col = (int*)ws;   ws += sizeof(int)*Eq;
    int*   cnt = (int*)ws;   ws += sizeof(int)*Nq;
    int*   rowstart = (int*)ws; ws += sizeof(int)*(Nq+1);
    int*   pos = (int*)ws;   ws += sizeof(int)*Nq;

    k_conv<<<Bq*NG8, 256, 0, stream>>>(x, wg1, bg1, wg2, bg2, wgcn, out1, xwt);
    k_graph_init <<<(Nq+255)/256, 256, 0, stream>>>(deg, cnt);
    k_graph_count<<<(Eq+255)/256, 256, 0, stream>>>(ei, ew, deg, cnt);
    k_graph_scan <<<1, 1024, 0, stream>>>(deg, cnt, dis, rowstart, pos);
    k_graph_fill <<<(Eq+255)/256, 256, 0, stream>>>(ei, ew, dis, pos, col, val);
    k_gcn<<<Nq, 256, 0, stream>>>(xwt, rowstart, col, val, dis,
                                  bgcn, wout, bout, y);
}

// Round 3
// 542.934 us; speedup vs baseline: 1.7101x; 1.1074x over previous
//
#include <hip/hip_runtime.h>
#include <math.h>

#define Bq 16
#define Tq 34
#define Nq 1000
#define Cq 32      // CIN == DC == 32
#define OCq 64
#define Eq 16000
#define TPq 32     // T - dilation
#define Gq (Bq*TPq)  // 512 graphs
#define NG8 (Nq/8)   // 125

__device__ __forceinline__ float fast_tanh(float x) {
    float xc = fminf(fmaxf(x, -15.f), 15.f);
    float u  = __expf(2.f * xc);
    return 1.f - 2.f * __builtin_amdgcn_rcpf(u + 1.f);
}
__device__ __forceinline__ float fast_sigmoid(float x) {
    float xc = fminf(fmaxf(x, -30.f), 30.f);
    return __builtin_amdgcn_rcpf(1.f + __expf(-xc));
}
__device__ __forceinline__ unsigned bf16_bits(float f) {
    unsigned u = __float_as_uint(f);
    return (u + 0x7fffu + ((u >> 16) & 1u)) >> 16;   // RNE
}
__device__ __forceinline__ unsigned pack_bf16x2(float lo, float hi) {
    return bf16_bits(lo) | (bf16_bits(hi) << 16);
}

// ---------------------------------------------------------------------------
// K1: fused dilated gated conv -> out1 [B,32,N,32] (fp32)  and
//     xwt = gated @ Wgcn^T packed bf16, layout uint4[(n*2+s)*4 + c8][gl]
//     (s = graph slice of 256, gl = g & 255) so k_gcn gathers are contiguous.
// block = 8 n x 32 t; x tile staged in LDS; weights in LDS (broadcast reads).
// ---------------------------------------------------------------------------
__global__ __launch_bounds__(256) void k_conv(
    const float* __restrict__ x,
    const float* __restrict__ wg1, const float* __restrict__ bg1,
    const float* __restrict__ wg2, const float* __restrict__ bg2,
    const float* __restrict__ wgcn,
    float* __restrict__ out1, uint4* __restrict__ xw4)
{
    __shared__ float xs[34*260];      // [t][n*32+c], stride 260 (16B-aligned pad)
    __shared__ float w1a[Cq*Cq], w1b[Cq*Cq], w2a[Cq*Cq], w2b[Cq*Cq];
    __shared__ float wgcT[Cq*Cq];     // wgcT[d*32+c] = wgcn[c*32+d]
    __shared__ float b1s[Cq], b2s[Cq];
    const int tid = threadIdx.x;
    const int b   = blockIdx.x / NG8;
    const int n0  = (blockIdx.x % NG8) * 8;

    for (int i = tid; i < Cq*Cq; i += 256) {
        w1a[i] = wg1[2*i];  w1b[i] = wg1[2*i+1];
        w2a[i] = wg2[2*i];  w2b[i] = wg2[2*i+1];
        wgcT[i] = wgcn[(i & 31)*Cq + (i >> 5)];
    }
    if (tid < Cq) { b1s[tid] = bg1[tid]; b2s[tid] = bg2[tid]; }
    const float* xsrc = x + ((size_t)b*Tq*Nq + n0)*Cq;
    #pragma unroll
    for (int j = 0; j < Tq; j++)
        xs[j*260 + tid] = xsrc[(size_t)j*Nq*Cq + tid];
    __syncthreads();

    const int t  = tid & 31;
    const int nl = tid >> 5;
    const int n  = n0 + nl;

    float x0[Cq], x1[Cq];
    #pragma unroll
    for (int c4 = 0; c4 < 8; c4++) {
        float4 a = *(const float4*)&xs[t*260 + nl*32 + 4*c4];
        x0[4*c4+0]=a.x; x0[4*c4+1]=a.y; x0[4*c4+2]=a.z; x0[4*c4+3]=a.w;
        float4 bb = *(const float4*)&xs[(t+2)*260 + nl*32 + 4*c4];
        x1[4*c4+0]=bb.x; x1[4*c4+1]=bb.y; x1[4*c4+2]=bb.z; x1[4*c4+3]=bb.w;
    }

    float xwa[Cq];
    #pragma unroll
    for (int c = 0; c < Cq; c++) xwa[c] = 0.f;

    float* o1base = out1 + (size_t)b*(Cq*Nq*TPq) + n*TPq + t;

    #pragma unroll
    for (int o = 0; o < Cq; o++) {
        float a1 = b1s[o], a2 = b2s[o];
        #pragma unroll
        for (int c4 = 0; c4 < 8; c4++) {
            const float4 va = *(const float4*)&w1a[o*Cq + 4*c4];
            const float4 vb = *(const float4*)&w1b[o*Cq + 4*c4];
            const float4 vc = *(const float4*)&w2a[o*Cq + 4*c4];
            const float4 vd = *(const float4*)&w2b[o*Cq + 4*c4];
            a1 = fmaf(x0[4*c4+0], va.x, a1); a1 = fmaf(x0[4*c4+1], va.y, a1);
            a1 = fmaf(x0[4*c4+2], va.z, a1); a1 = fmaf(x0[4*c4+3], va.w, a1);
            a1 = fmaf(x1[4*c4+0], vb.x, a1); a1 = fmaf(x1[4*c4+1], vb.y, a1);
            a1 = fmaf(x1[4*c4+2], vb.z, a1); a1 = fmaf(x1[4*c4+3], vb.w, a1);
            a2 = fmaf(x0[4*c4+0], vc.x, a2); a2 = fmaf(x0[4*c4+1], vc.y, a2);
            a2 = fmaf(x0[4*c4+2], vc.z, a2); a2 = fmaf(x0[4*c4+3], vc.w, a2);
            a2 = fmaf(x1[4*c4+0], vd.x, a2); a2 = fmaf(x1[4*c4+1], vd.y, a2);
            a2 = fmaf(x1[4*c4+2], vd.z, a2); a2 = fmaf(x1[4*c4+3], vd.w, a2);
        }
        const float go = fast_tanh(a1) * fast_sigmoid(a2);
        o1base[(size_t)o * (Nq*TPq)] = go;
        #pragma unroll
        for (int c4 = 0; c4 < 8; c4++) {
            const float4 w = *(const float4*)&wgcT[o*Cq + 4*c4];
            xwa[4*c4+0] = fmaf(go, w.x, xwa[4*c4+0]);
            xwa[4*c4+1] = fmaf(go, w.y, xwa[4*c4+1]);
            xwa[4*c4+2] = fmaf(go, w.z, xwa[4*c4+2]);
            xwa[4*c4+3] = fmaf(go, w.w, xwa[4*c4+3]);
        }
    }

    // bf16-pack + swizzled write: g = b*32 + t == (b*Tp + t)
    const int g  = b*32 + t;
    const int s  = g >> 8;
    const int gl = g & 255;
    #pragma unroll
    for (int c8 = 0; c8 < 4; c8++) {
        uint4 u;
        u.x = pack_bf16x2(xwa[8*c8+0], xwa[8*c8+1]);
        u.y = pack_bf16x2(xwa[8*c8+2], xwa[8*c8+3]);
        u.z = pack_bf16x2(xwa[8*c8+4], xwa[8*c8+5]);
        u.w = pack_bf16x2(xwa[8*c8+6], xwa[8*c8+7]);
        xw4[((size_t)(n*2 + s)*4 + c8)*256 + gl] = u;
    }
}

// ---------------------------------------------------------------------------
// Single-block graph prep: LDS degree/count atomics -> LDS scan -> CSR fill.
// Replaces 4 kernel launches.
// ---------------------------------------------------------------------------
__global__ __launch_bounds__(1024) void k_graph(
    const int* __restrict__ ei, const float* __restrict__ ew,
    float* __restrict__ dis_g, int* __restrict__ rowstart_g,
    int* __restrict__ col, float* __restrict__ val)
{
    __shared__ float deg[Nq];
    __shared__ int   cnt[Nq];
    __shared__ int   pos[Nq];
    __shared__ float diss[Nq];
    __shared__ int   ssum[1024];
    const int tid = threadIdx.x;

    for (int n = tid; n < Nq; n += 1024) { deg[n] = 1.0f; cnt[n] = 0; }
    __syncthreads();
    for (int e = tid; e < Eq; e += 1024) {
        int d = ei[Eq + e];
        atomicAdd(&deg[d], ew[e]);
        atomicAdd(&cnt[d], 1);
    }
    __syncthreads();
    const int v = (tid < Nq) ? cnt[tid] : 0;
    ssum[tid] = v;
    __syncthreads();
    for (int off = 1; off < 1024; off <<= 1) {
        int add = (tid >= off) ? ssum[tid - off] : 0;
        __syncthreads();
        ssum[tid] += add;
        __syncthreads();
    }
    if (tid < Nq) {
        int excl = ssum[tid] - v;
        pos[tid] = excl;
        rowstart_g[tid] = excl;
        float di = rsqrtf(deg[tid]);    // deg >= 1 (self loop)
        diss[tid] = di;
        dis_g[tid] = di;
        if (tid == Nq-1) rowstart_g[Nq] = ssum[tid];
    }
    __syncthreads();
    for (int e = tid; e < Eq; e += 1024) {
        int srce = ei[e], d = ei[Eq + e];
        int slot = atomicAdd(&pos[d], 1);
        col[slot] = srce;
        val[slot] = diss[srce] * ew[e] * diss[d];
    }
}

// ---------------------------------------------------------------------------
// K3: SpMM gather + fused 1x1 conv. Grid = 2 slices x 1000 rows (slice-major
// for L2/L3 locality: per-slice working set = 16 MB bf16). Thread = one graph
// (32-c accumulator in regs). Per edge: 4 x 16B coalesced loads (1KB/wave).
// ---------------------------------------------------------------------------
__global__ __launch_bounds__(256) void k_gcn(
    const uint4* __restrict__ xw4, const int* __restrict__ rowstart,
    const int* __restrict__ colv, const float* __restrict__ valv,
    const float* __restrict__ dis, const float* __restrict__ bgcn,
    const float* __restrict__ wout, const float* __restrict__ bout,
    float* __restrict__ y)
{
    __shared__ float woT[Cq*OCq];   // woT[c*64+o] = wout[o*32+c]
    __shared__ int   scol[64];
    __shared__ float sval[64];
    const int tid = threadIdx.x;
    const int s   = blockIdx.x / Nq;
    const int i   = blockIdx.x - s*Nq;

    for (int k = tid; k < Cq*OCq; k += 256) {
        int o = k & 63, c = k >> 6;
        woT[k] = wout[o*Cq + c];    // consecutive LDS writes: conflict-free
    }

    float acc[Cq];
    #pragma unroll
    for (int c = 0; c < Cq; c++) acc[c] = 0.f;

    const int r0 = rowstart[i], r1 = rowstart[i+1];
    const int total = r1 - r0 + 1;       // + self loop
    const float dii = dis[i];

    for (int base = 0; base < total; base += 64) {
        const int cnt = min(64, total - base);
        __syncthreads();
        if (tid < cnt) {
            int k = base + tid;
            if (k == 0) { scol[tid] = i; sval[tid] = dii*dii; }
            else        { scol[tid] = colv[r0 + k - 1]; sval[tid] = valv[r0 + k - 1]; }
        }
        __syncthreads();
        for (int k = 0; k < cnt; k++) {
            const int   sc = scol[k];
            const float sv = sval[k];
            const uint4* rp = xw4 + ((size_t)(sc*2 + s)*4)*256 + tid;
            uint4 v[4];
            #pragma unroll
            for (int c8 = 0; c8 < 4; c8++) v[c8] = rp[c8*256];
            #pragma unroll
            for (int c8 = 0; c8 < 4; c8++) {
                acc[8*c8+0] = fmaf(sv, __uint_as_float(v[c8].x << 16),          acc[8*c8+0]);
                acc[8*c8+1] = fmaf(sv, __uint_as_float(v[c8].x & 0xffff0000u), acc[8*c8+1]);
                acc[8*c8+2] = fmaf(sv, __uint_as_float(v[c8].y << 16),          acc[8*c8+2]);
                acc[8*c8+3] = fmaf(sv, __uint_as_float(v[c8].y & 0xffff0000u), acc[8*c8+3]);
                acc[8*c8+4] = fmaf(sv, __uint_as_float(v[c8].z << 16),          acc[8*c8+4]);
                acc[8*c8+5] = fmaf(sv, __uint_as_float(v[c8].z & 0xffff0000u), acc[8*c8+5]);
                acc[8*c8+6] = fmaf(sv, __uint_as_float(v[c8].w << 16),          acc[8*c8+6]);
                acc[8*c8+7] = fmaf(sv, __uint_as_float(v[c8].w & 0xffff0000u), acc[8*c8+7]);
            }
        }
    }

    #pragma unroll
    for (int c4 = 0; c4 < 8; c4++) {
        const float4 bg = *(const float4*)&bgcn[4*c4];   // uniform
        acc[4*c4+0] += bg.x; acc[4*c4+1] += bg.y;
        acc[4*c4+2] += bg.z; acc[4*c4+3] += bg.w;
    }

    // fused 1x1 out-conv, two 32-output halves (register-bounded)
    const int g = s*256 + tid;
    float* yp = y + ((size_t)g*Nq + i)*OCq;
    #pragma unroll
    for (int h = 0; h < 2; h++) {
        float yr[32];
        #pragma unroll
        for (int q = 0; q < 32; q++) yr[q] = bout[h*32 + q];   // uniform
        #pragma unroll
        for (int c = 0; c < Cq; c++) {
            const float ga = acc[c];
            const float* wrow = &woT[c*OCq + h*32];
            #pragma unroll
            for (int q4 = 0; q4 < 8; q4++) {
                const float4 w = *(const float4*)&wrow[4*q4];  // broadcast
                yr[4*q4+0] = fmaf(ga, w.x, yr[4*q4+0]);
                yr[4*q4+1] = fmaf(ga, w.y, yr[4*q4+1]);
                yr[4*q4+2] = fmaf(ga, w.z, yr[4*q4+2]);
                yr[4*q4+3] = fmaf(ga, w.w, yr[4*q4+3]);
            }
        }
        #pragma unroll
        for (int q4 = 0; q4 < 8; q4++) {
            float4 vv;
            vv.x = yr[4*q4+0]; vv.y = yr[4*q4+1];
            vv.z = yr[4*q4+2]; vv.w = yr[4*q4+3];
            *(float4*)&yp[h*32 + 4*q4] = vv;
        }
    }
}

// ---------------------------------------------------------------------------
extern "C" void kernel_launch(void* const* d_in, const int* in_sizes, int n_in,
                              void* d_out, int out_size, void* d_ws, size_t ws_size,
                              hipStream_t stream)
{
    const float* x    = (const float*)d_in[0];
    const int*   ei   = (const int*)  d_in[1];
    const float* ew   = (const float*)d_in[2];
    const float* wg1  = (const float*)d_in[3];
    const float* bg1  = (const float*)d_in[4];
    const float* wg2  = (const float*)d_in[5];
    const float* bg2  = (const float*)d_in[6];
    const float* wgcn = (const float*)d_in[7];
    const float* bgcn = (const float*)d_in[8];
    const float* wout = (const float*)d_in[9];
    const float* bout = (const float*)d_in[10];

    float* out1 = (float*)d_out;                         // [B,32,N,32]
    float* y    = out1 + (size_t)Bq*Cq*Nq*TPq;           // [B,32,N,64]

    char* ws = (char*)d_ws;
    uint4* xwt = (uint4*)ws; ws += sizeof(unsigned short)*(size_t)Nq*Gq*Cq; // 32.8MB
    float* dis = (float*)ws; ws += sizeof(float)*Nq;
    float* val = (float*)ws; ws += sizeof(float)*Eq;
    int*   col = (int*)ws;   ws += sizeof(int)*Eq;
    int*   rowstart = (int*)ws; ws += sizeof(int)*(Nq+4);

    k_conv<<<Bq*NG8, 256, 0, stream>>>(x, wg1, bg1, wg2, bg2, wgcn, out1, xwt);
    k_graph<<<1, 1024, 0, stream>>>(ei, ew, dis, rowstart, col, val);
    k_gcn<<<2*Nq, 256, 0, stream>>>(xwt, rowstart, col, val, dis,
                                    bgcn, wout, bout, y);
}